// Round 9
// baseline (2520.446 us; speedup 1.0000x reference)
//
#include <hip/hip_runtime.h>
#include <math.h>

#define NB    4096   // batch N
#define FEAT  1024
#define MSUP  512    // SUPPORT
#define G4    4096   // 4*FEAT
#define NWAYS 20     // n_ways fixed to 20 per setup_inputs()

typedef _Float16 f16;
typedef f16 f16x8 __attribute__((ext_vector_type(8)));
typedef f16 f16x4 __attribute__((ext_vector_type(4)));
typedef float f32x4 __attribute__((ext_vector_type(4)));
typedef unsigned int u32;
#define GLOBAL_AS __attribute__((address_space(1)))
#define LDS_AS    __attribute__((address_space(3)))

__device__ __forceinline__ void load_lds16(const void* g, void* l) {
    __builtin_amdgcn_global_load_lds((const GLOBAL_AS u32*)g, (LDS_AS u32*)l, 16, 0, 0);
}

__device__ __forceinline__ float sigm(float x) { return 1.f / (1.f + __expf(-x)); }

// ---------------- plain f16 MFMA NT GEMM (R2-proven core) ----------------
template<int BM, int BN, int WROWS, int WCOLS, bool OUTF16, bool HASBIAS>
__global__ __launch_bounds__(256) void mfma_nt(
    void* __restrict__ Cv, int ldc,
    const f16* __restrict__ A1, int lda1, const f16* __restrict__ B1, int ldb1, int K1,
    const f16* __restrict__ A2, int lda2, const f16* __restrict__ B2, int ldb2, int K2,
    const f16* __restrict__ A3, int lda3, const f16* __restrict__ B3, int ldb3, int K3,
    const float* __restrict__ bias)
{
    constexpr int BK = 32;
    constexpr int WM = BM / WROWS, WN = BN / WCOLS;
    constexpr int FM = WM / 16,   FN = WN / 16;
    __shared__ f16 As[BM][BK];
    __shared__ f16 Bs[BN][BK];
    const int tid  = threadIdx.x;
    const int lane = tid & 63;
    const int wrow = (tid >> 6) % WROWS, wcol = (tid >> 6) / WROWS;
    const int bm = blockIdx.y * BM, bn = blockIdx.x * BN;
    const int lr = lane & 15, lq = lane >> 4;

    f32x4 acc[FM][FN] = {};

    #pragma unroll
    for (int pass = 0; pass < 3; ++pass) {
        const f16* A = pass == 0 ? A1 : (pass == 1 ? A2 : A3);
        const f16* B = pass == 0 ? B1 : (pass == 1 ? B2 : B3);
        const int lda = pass == 0 ? lda1 : (pass == 1 ? lda2 : lda3);
        const int ldb = pass == 0 ? ldb1 : (pass == 1 ? ldb2 : ldb3);
        const int K   = pass == 0 ? K1  : (pass == 1 ? K2  : K3);
        if (!A) break;
        #pragma unroll 1
        for (int k0 = 0; k0 < K; k0 += BK) {
            __syncthreads();
            #pragma unroll
            for (int t = 0; t < (BM * 4) / 256; ++t) {
                int c = t * 256 + tid;
                load_lds16(A + (size_t)(bm + (c >> 2)) * lda + k0 + (c & 3) * 8,
                           &As[0][0] + ((size_t)t * 256 + (tid & 192)) * 8);
            }
            #pragma unroll
            for (int t = 0; t < (BN * 4) / 256; ++t) {
                int c = t * 256 + tid;
                load_lds16(B + (size_t)(bn + (c >> 2)) * ldb + k0 + (c & 3) * 8,
                           &Bs[0][0] + ((size_t)t * 256 + (tid & 192)) * 8);
            }
            __syncthreads();
            f16x8 af[FM], bf[FN];
            #pragma unroll
            for (int i = 0; i < FM; ++i)
                af[i] = *(const f16x8*)&As[wrow * WM + i * 16 + lr][lq * 8];
            #pragma unroll
            for (int j = 0; j < FN; ++j)
                bf[j] = *(const f16x8*)&Bs[wcol * WN + j * 16 + lr][lq * 8];
            #pragma unroll
            for (int i = 0; i < FM; ++i)
                #pragma unroll
                for (int j = 0; j < FN; ++j)
                    acc[i][j] = __builtin_amdgcn_mfma_f32_16x16x32_f16(af[i], bf[j], acc[i][j], 0, 0, 0);
        }
    }

    #pragma unroll
    for (int i = 0; i < FM; ++i) {
        #pragma unroll
        for (int j = 0; j < FN; ++j) {
            const int col  = bn + wcol * WN + j * 16 + lr;
            const int row0 = bm + wrow * WM + i * 16 + lq * 4;
            float badd = HASBIAS ? bias[col] : 0.f;
            #pragma unroll
            for (int r = 0; r < 4; ++r) {
                size_t off = (size_t)(row0 + r) * ldc + col;
                float v = acc[i][j][r] + badd;
                if (OUTF16) ((f16*)Cv)[off] = (f16)v;
                else        ((float*)Cv)[off] = v;
            }
        }
    }
}

// ------------- fused gates GEMM + LSTM cell — m97-EXACT structure (R9) -------------
// R6/R8 verdict: 6 schedule variants at 1-block/CU all ~98-110us; the measured m97
// ladder point (912 TF ref-checked on this chip = 75us for this GEMM) uses a
// DIFFERENT overlap mechanism: 3 blocks/CU inter-block co-scheduling (m114), from
//   128^2 tile + BK=32 + SINGLE-buffered 16 KB LDS + plain 2x__syncthreads K-loop
//   (compiler-inserted drains; the other 2 blocks on the CU fill the drain window).
// R7 failed this by using BK=64 dbuf (64 KB -> 2 blocks/CU; m132's documented
// regression). This kernel is the m97 recipe verbatim + our fused cell epilogue.
// Swizzle (BK=32, 4x16B chunks/row): LDS slot s of row r holds global chunk
// s^(r&3); read slot = lq^(lr&3) (row bases are %4==0). Residual 2-way bank
// aliasing only (free, m136). Staging: 4 gload_lds16/thread/K-step, linear dest.
__global__ __launch_bounds__(256, 3) void gates_m97(
    const f16* __restrict__ a,     // [NB][MSUP]
    const f16* __restrict__ h,     // [NB][FEAT]
    const f16* __restrict__ Wcat,  // [G4][2048] permuted rows
    const f16* __restrict__ pre,   // [NB][G4] (permuted cols)
    const float* __restrict__ fin, // [NB][FEAT] f32
    float* __restrict__ cbuf,      // block-private c, f32 (must stay f32)
    f16* __restrict__ hh,          // [NB][FEAT] f16 h_next
    float* __restrict__ hout,      // [NB][FEAT] f32 (writeH)
    int first, int writeH)
{
    __shared__ f16 As[128][32];
    __shared__ f16 Bs[128][32];
    const int tid  = threadIdx.x;
    const int lane = tid & 63;
    const int wid  = tid >> 6;
    const int wrow = wid >> 1, wcol = wid & 1;   // 2x2 waves, 64x64 each
    const int lr = lane & 15, lq = lane >> 4;

    // T1: bijective XCD swizzle (1024 blocks, 1024%8==0)
    const int bidr = blockIdx.y * 32 + blockIdx.x;
    const int wg   = (bidr & 7) * 128 + (bidr >> 3);
    const int bm = (wg >> 5) * 128;   // batch rows
    const int bn = (wg & 31) * 128;   // gate cols

    f32x4 acc[4][4] = {};

    // staging: 512 x 16B chunks per 128x32 tile, 2 per thread (l=0,1).
    // c = l*256+tid: row r = l*64 + (tid>>2), slot s = tid&3,
    // global chunk x = s ^ (r&3) = (tid&3)^((tid>>2)&3)  (l*64 ≡ 0 mod 4).
    const int rr4 = tid >> 2;
    const int xx4 = ((tid & 3) ^ (rr4 & 3)) << 3;      // f16 offset within row
    auto stage = [&](const f16* src, int ld, int rb, int ko, f16* lbase, int l) {
        load_lds16(src + (size_t)(rb + l * 64 + rr4) * ld + ko + xx4,
                   lbase + ((size_t)(l * 256 + (tid & 192))) * 8);
    };

    #pragma unroll 1
    for (int k0 = 0; k0 < 2048; k0 += 32) {
        const f16* Asrc = a; int lda = MSUP, ko = k0;
        if (k0 >= 1024)     { Asrc = h; lda = FEAT; ko = k0 - 1024; }
        else if (k0 >= 512) { ko = k0 - 512; }

        __syncthreads();                 // all reads of previous tile done
        stage(Asrc, lda, bm, ko, &As[0][0], 0);
        stage(Asrc, lda, bm, ko, &As[0][0], 1);
        stage(Wcat, 2048, bn, k0, &Bs[0][0], 0);
        stage(Wcat, 2048, bn, k0, &Bs[0][0], 1);
        __syncthreads();                 // compiler-inserted vmcnt drain precedes this

        f16x8 af[4], bf[4];
        #pragma unroll
        for (int i = 0; i < 4; ++i) {
            int r = wrow * 64 + i * 16 + lr;
            af[i] = *(const f16x8*)&As[r][(lq ^ (lr & 3)) * 8];
        }
        #pragma unroll
        for (int j = 0; j < 4; ++j) {
            int r = wcol * 64 + j * 16 + lr;
            bf[j] = *(const f16x8*)&Bs[r][(lq ^ (lr & 3)) * 8];
        }
        #pragma unroll
        for (int i = 0; i < 4; ++i)
            #pragma unroll
            for (int j = 0; j < 4; ++j)
                acc[i][j] = __builtin_amdgcn_mfma_f32_16x16x32_f16(af[i], bf[j], acc[i][j], 0, 0, 0);
    }

    // ---- fused cell epilogue (quad-transpose per 16x16 fragment, R7-verified) ----
    const int q  = lane & 3;
    const int fk = (lane >> 2) & 3;
    #pragma unroll
    for (int i = 0; i < 4; ++i) {
        #pragma unroll
        for (int j = 0; j < 4; ++j) {
            const int cb   = bn + wcol * 64 + j * 16;
            const int row0 = bm + wrow * 64 + i * 16 + lq * 4;
            float x[4];
            #pragma unroll
            for (int r = 0; r < 4; ++r) x[r] = acc[i][j][r];
            float g4[4];
            #pragma unroll
            for (int k = 0; k < 4; ++k) {
                int srcq = (q + k) & 3;
                int src  = (lane & ~3) | srcq;
                g4[srcq] = __shfl(x[(q - k + 4) & 3], src, 64);
            }
            const int row  = row0 + q;
            const int feat = (cb >> 2) + fk;
            f16x4 p = *(const f16x4*)(pre + (size_t)row * G4 + cb + 4 * fk);
            const float i_ = sigm(g4[0] + (float)p[0]);
            const float f_ = sigm(g4[1] + (float)p[1]);
            const float g_ = tanhf(g4[2] + (float)p[2]);
            const float o_ = sigm(g4[3] + (float)p[3]);
            const size_t cid = ((size_t)(blockIdx.y * gridDim.x + blockIdx.x) * 16
                                + i * 4 + j) * 256 + tid;
            float cold = first ? 0.f : cbuf[cid];
            float cn = i_ * g_ + f_ * cold;
            cbuf[cid] = cn;                 // f32 — f16 here injects 2.4e-4/iter
            float hn = o_ * tanhf(cn) + fin[(size_t)row * FEAT + feat];
            hh[(size_t)row * FEAT + feat] = (f16)hn;
            if (writeH) hout[(size_t)row * FEAT + feat] = hn;
        }
    }
}

// -------- softmax along contiguous rows; in f32 [rows][4096] -> out f16 --------
__global__ __launch_bounds__(256) void softmax_rows_kernel(
    const float* __restrict__ X, f16* __restrict__ Y)
{
    const int row = blockIdx.x;
    const float* x = X + (size_t)row * NB;
    f16* y = Y + (size_t)row * NB;
    const int tid = threadIdx.x;
    float v[16];
    float mx = -1e30f;
    #pragma unroll
    for (int i = 0; i < 16; ++i) { v[i] = x[tid + (i << 8)]; mx = fmaxf(mx, v[i]); }
    #pragma unroll
    for (int off = 32; off > 0; off >>= 1) mx = fmaxf(mx, __shfl_down(mx, off));
    __shared__ float sm[4];
    if ((tid & 63) == 0) sm[tid >> 6] = mx;
    __syncthreads();
    mx = fmaxf(fmaxf(sm[0], sm[1]), fmaxf(sm[2], sm[3]));
    float s = 0.f;
    #pragma unroll
    for (int i = 0; i < 16; ++i) { v[i] = __expf(v[i] - mx); s += v[i]; }
    #pragma unroll
    for (int off = 32; off > 0; off >>= 1) s += __shfl_down(s, off);
    __shared__ float ss[4];
    if ((tid & 63) == 0) ss[tid >> 6] = s;
    __syncthreads();
    s = ss[0] + ss[1] + ss[2] + ss[3];
    const float inv = 1.f / s;
    #pragma unroll
    for (int i = 0; i < 16; ++i) y[tid + (i << 8)] = (f16)(v[i] * inv);
}

// -------- transpose: f16 [R][C] -> f16 [C][R] --------
__global__ __launch_bounds__(256) void transpose_f16_kernel(
    const f16* __restrict__ in, f16* __restrict__ out, int R, int C)
{
    __shared__ f16 t[64][65];
    const int r0 = blockIdx.y * 64, c0 = blockIdx.x * 64;
    const int lr = threadIdx.x & 63, lw = threadIdx.x >> 6;
    #pragma unroll
    for (int i = 0; i < 16; ++i) {
        int rr = lw * 16 + i;
        t[rr][lr] = in[(size_t)(r0 + rr) * C + c0 + lr];
    }
    __syncthreads();
    #pragma unroll
    for (int i = 0; i < 16; ++i) {
        int cc = lw * 16 + i;
        out[(size_t)(c0 + cc) * R + r0 + lr] = t[lr][cc];
    }
}

// -------- f32 -> f16 convert --------
__global__ __launch_bounds__(256) void cvt_f16_kernel(
    const float* __restrict__ in, f16* __restrict__ out, int n)
{
    int idx = (blockIdx.x * 256 + threadIdx.x) * 4;
    if (idx < n) {
        float4 v = *(const float4*)(in + idx);
        f16x4 o = {(f16)v.x, (f16)v.y, (f16)v.z, (f16)v.w};
        *(f16x4*)(out + idx) = o;
    }
}

// -------- row-permuted f16 conversion with dst stride/offset --------
__global__ __launch_bounds__(256) void cvt_perm_kernel(
    const float* __restrict__ in, f16* __restrict__ out, int ld_in, int ld_out, int col_off)
{
    int idx = (blockIdx.x * 256 + threadIdx.x) * 4;
    int j = idx / ld_in, k = idx % ld_in;
    int dst = 4 * (j & 1023) + (j >> 10);
    float4 v = *(const float4*)(in + idx);
    f16x4 o = {(f16)v.x, (f16)v.y, (f16)v.z, (f16)v.w};
    *(f16x4*)(out + (size_t)dst * ld_out + col_off + k) = o;
}

// -------- permuted combined bias --------
__global__ __launch_bounds__(256) void bias_perm_kernel(
    const float* __restrict__ bih, const float* __restrict__ bhh, float* __restrict__ out)
{
    int j = blockIdx.x * 256 + threadIdx.x;
    out[4 * (j & 1023) + (j >> 10)] = bih[j] + bhh[j];
}

// -------- Wr32 [G4][512] f32 -> Wcat hi/lo halves --------
__global__ __launch_bounds__(256) void split_wcat_kernel(
    const float* __restrict__ in, f16* __restrict__ out)
{
    int idx = (blockIdx.x * 256 + threadIdx.x) * 4;   // over G4*MSUP
    int g = idx >> 9, k = idx & 511;
    float4 v = *(const float4*)(in + idx);
    f16x4 hi = {(f16)v.x, (f16)v.y, (f16)v.z, (f16)v.w};
    f16x4 lo = {(f16)(v.x - (float)hi.x), (f16)(v.y - (float)hi.y),
                (f16)(v.z - (float)hi.z), (f16)(v.w - (float)hi.w)};
    *(f16x4*)(out + (size_t)g * 2048 + k) = hi;
    *(f16x4*)(out + (size_t)g * 2048 + 512 + k) = lo;
}

extern "C" void kernel_launch(void* const* d_in, const int* in_sizes, int n_in,
                              void* d_out, int out_size, void* d_ws, size_t ws_size,
                              hipStream_t stream) {
    const float* f   = (const float*)d_in[0];   // [NB, FEAT]
    const float* G   = (const float*)d_in[1];   // [MSUP, FEAT]
    const float* Wih = (const float*)d_in[2];   // [G4, 2*FEAT]
    const float* Whh = (const float*)d_in[3];   // [G4, FEAT]
    const float* bih = (const float*)d_in[4];   // [G4]
    const float* bhh = (const float*)d_in[5];   // [G4]
    float* h = (float*)d_out;                   // [NB, FEAT]

    char* W = (char*)d_ws;
    f16*   pre_h   = (f16*)(W);                          // 32 MB [NB][G4] (permuted cols)
    float* aT      = (float*)(W + (size_t)(32 << 20));   //  8 MB [MSUP][NB]
    f16*   aTh     = (f16*)(W + (size_t)(40 << 20));     //  4 MB [MSUP][NB]
    f16*   a_h     = (f16*)(W + (size_t)(44 << 20));     //  4 MB [NB][MSUP]
    float* cbuf    = (float*)(W + (size_t)(48 << 20));   // 16 MB block-private c (f32!)
    f16*   h0      = (f16*)(W + (size_t)(64 << 20));     //  8 MB [NB][FEAT] = f16(f)
    f16*   hA      = (f16*)(W + (size_t)(72 << 20));     //  8 MB h ping
    f16*   hB      = (f16*)(W + (size_t)(80 << 20));     //  8 MB h pong
    f16*   Wih_h   = (f16*)(W + (size_t)(88 << 20));     // 16 MB [G4][2F] (permuted rows)
    f16*   Wcat    = (f16*)(W + (size_t)(104 << 20));    // 16 MB [G4][2048] = [Wr_hi|Wr_lo|Whh]
    float* Wr32    = (float*)(W + (size_t)(120 << 20));  //  8 MB [G4][MSUP] (permuted rows)
    f16*   G_h     = (f16*)(W + (size_t)(128 << 20));    //  1 MB [MSUP][FEAT]
    float* bias_p  = (float*)(W + (size_t)(129 << 20));  // 16 KB

    const f16* NF = nullptr;
    const dim3 blk(256);

    // setup (every call — ws is re-poisoned)
    cvt_f16_kernel<<<(NB * FEAT) / 1024, blk, 0, stream>>>(f, h0, NB * FEAT);
    cvt_perm_kernel<<<(G4 * 2 * FEAT) / 1024, blk, 0, stream>>>(Wih, Wih_h, 2 * FEAT, 2 * FEAT, 0);
    cvt_perm_kernel<<<(G4 * FEAT) / 1024, blk, 0, stream>>>(Whh, Wcat, FEAT, 2048, 1024);
    cvt_f16_kernel<<<(MSUP * FEAT) / 1024, blk, 0, stream>>>(G, G_h, MSUP * FEAT);
    bias_perm_kernel<<<G4 / 256, blk, 0, stream>>>(bih, bhh, bias_p);

    // pre = f @ W_f^T + biases (permuted cols; constant across iterations)
    mfma_nt<128, 128, 2, 2, true, true><<<dim3(G4 / 128, NB / 128), blk, 0, stream>>>(
        pre_h, G4,
        h0, FEAT, Wih_h, 2 * FEAT, FEAT,
        NF, 0, NF, 0, 0, NF, 0, NF, 0, 0,
        bias_p);

    // Wr' = W_r @ G^T in f32 (permuted rows), then hi/lo f16 split into Wcat cols 0..1023
    mfma_nt<128, 128, 2, 2, false, false><<<dim3(MSUP / 128, G4 / 128), blk, 0, stream>>>(
        Wr32, MSUP,
        Wih_h + FEAT, 2 * FEAT, G_h, FEAT, FEAT,
        NF, 0, NF, 0, 0, NF, 0, NF, 0, 0,
        nullptr);
    split_wcat_kernel<<<(G4 * MSUP) / 1024, blk, 0, stream>>>(Wr32, Wcat);

    const f16* hcur = h0;
    for (int it = 0; it < NWAYS; ++it) {
        // aT[m][n] = G[m]·h[n] (transposed → contiguous row softmax)
        mfma_nt<64, 64, 2, 2, false, false><<<dim3(NB / 64, MSUP / 64), blk, 0, stream>>>(
            aT, NB,
            G_h, FEAT, hcur, FEAT, FEAT,
            NF, 0, NF, 0, 0, NF, 0, NF, 0, 0,
            nullptr);

        softmax_rows_kernel<<<MSUP, blk, 0, stream>>>(aT, aTh);
        transpose_f16_kernel<<<dim3(NB / 64, MSUP / 64), blk, 0, stream>>>(aTh, a_h, MSUP, NB);

        // gates = pre + [a|a|h] @ Wcat^T, fused LSTM cell epilogue (m97 structure)
        f16* hnext = (it & 1) ? hB : hA;
        gates_m97<<<dim3(32, 32), blk, 0, stream>>>(
            a_h, hcur, Wcat, pre_h, f, cbuf, hnext, h, it == 0, it == NWAYS - 1);
        hcur = hnext;
    }
}